// Round 1
// baseline (263.851 us; speedup 1.0000x reference)
//
#include <hip/hip_runtime.h>
#include <hip/hip_bf16.h>
#include <cstdint>
#include <cstddef>

typedef __attribute__((ext_vector_type(8))) short short8;
typedef __attribute__((ext_vector_type(4))) float f32x4;

static constexpr int B_ = 16, N_ = 1024, F_ = 768, H_ = 12, D_ = 64;
static constexpr int QB = 64, NB = 64;
static constexpr int KP = 72, VP = 72, PP = 72;
static constexpr float RSCALE = 0.036084391824351615f; // 1/sqrt(768)

__device__ __forceinline__ short f2bf(float f) {
    uint32_t u = __builtin_bit_cast(uint32_t, f);
    u += 0x7fffu + ((u >> 16) & 1u);   // round-to-nearest-even (no NaN in this problem)
    return (short)(u >> 16);
}

__global__ void __launch_bounds__(256) attn_fused(
    const float* __restrict__ x,
    const float* __restrict__ wq, const float* __restrict__ bq,
    const float* __restrict__ wk, const float* __restrict__ bk,
    const float* __restrict__ wv, const float* __restrict__ bv,
    const float* __restrict__ wo, const float* __restrict__ bo,
    float* __restrict__ out)
{
    __shared__ short Klds[NB][KP];        // K tile, row-major [n][d], padded
    __shared__ short Vt[D_][VP];          // V tile, transposed [d][n], padded
    __shared__ short Plds[4][16][PP];     // per-wave P tile [qrow][n], padded

    const int tid  = threadIdx.x;
    const int wave = tid >> 6;
    const int lane = tid & 63;
    const int g    = lane >> 4;   // 0..3
    const int cc   = lane & 15;   // 0..15

    const int bid = blockIdx.x;
    const int qt  = bid & 15;          // N/QB = 16
    const int t1  = bid >> 4;
    const int h   = t1 % H_;
    const int b   = t1 / H_;

    // ---- Q fragments (per wave: rows qt*64 + wave*16 .. +15), scale folded in ----
    const int qrow = qt * QB + wave * 16 + cc;
    const float* xq = x + ((size_t)(b * N_ + qrow)) * F_ + h * D_;
    short8 qf[2];
    #pragma unroll
    for (int kc = 0; kc < 2; ++kc) {
        const int dd = kc * 32 + g * 8;
        float4 a0 = *(const float4*)(xq + dd);
        float4 a1 = *(const float4*)(xq + dd + 4);
        float qa[8] = {a0.x,a0.y,a0.z,a0.w,a1.x,a1.y,a1.z,a1.w};
        #pragma unroll
        for (int i = 0; i < 8; ++i) {
            const int ch = h * D_ + dd + i;
            qf[kc][i] = f2bf((qa[i] * wq[ch] + bq[ch]) * RSCALE);
        }
    }

    // staging coords: each thread stages 16 channels of one K/V row
    const int srow = tid >> 2;   // 0..63
    const int seg  = tid & 3;    // 0..3
    const int cb   = h * D_ + seg * 16;

    float m_[4], l_[4];
    f32x4 oacc[4];
    #pragma unroll
    for (int r = 0; r < 4; ++r) {
        m_[r] = -INFINITY; l_[r] = 0.f;
        oacc[r] = (f32x4){0.f, 0.f, 0.f, 0.f};
    }

    for (int nb = 0; nb < N_; nb += NB) {
        __syncthreads();   // previous tile's compute done before overwrite
        // ---- stage K (row-major bf16) and V^T (transposed bf16) ----
        {
            const float* xr = x + ((size_t)(b * N_ + nb + srow)) * F_ + cb;
            float4 x0 = *(const float4*)(xr + 0);
            float4 x1 = *(const float4*)(xr + 4);
            float4 x2 = *(const float4*)(xr + 8);
            float4 x3 = *(const float4*)(xr + 12);
            float xf[16] = {x0.x,x0.y,x0.z,x0.w, x1.x,x1.y,x1.z,x1.w,
                            x2.x,x2.y,x2.z,x2.w, x3.x,x3.y,x3.z,x3.w};
            short8 k0, k1;
            #pragma unroll
            for (int i = 0; i < 8; ++i) {
                k0[i] = f2bf(xf[i]     * wk[cb + i]     + bk[cb + i]);
                k1[i] = f2bf(xf[i + 8] * wk[cb + i + 8] + bk[cb + i + 8]);
            }
            *(short8*)&Klds[srow][seg * 16]     = k0;
            *(short8*)&Klds[srow][seg * 16 + 8] = k1;
            #pragma unroll
            for (int i = 0; i < 16; ++i)
                Vt[seg * 16 + i][srow] = f2bf(xf[i] * wv[cb + i] + bv[cb + i]);
        }
        __syncthreads();

        // ---- S = Q K^T  (A = Q frag, B = K frag; D 16x16 per n-subtile) ----
        f32x4 s[4];
        #pragma unroll
        for (int sub = 0; sub < 4; ++sub) {
            f32x4 acc = (f32x4){0.f, 0.f, 0.f, 0.f};
            #pragma unroll
            for (int kc = 0; kc < 2; ++kc) {
                short8 kf = *(short8*)&Klds[sub * 16 + cc][kc * 32 + g * 8];
                acc = __builtin_amdgcn_mfma_f32_16x16x32_bf16(qf[kc], kf, acc, 0, 0, 0);
            }
            s[sub] = acc;
        }

        // ---- online softmax (rows = 4*g + r, cols across 16 lanes) ----
        float tm[4];
        #pragma unroll
        for (int r = 0; r < 4; ++r)
            tm[r] = fmaxf(fmaxf(s[0][r], s[1][r]), fmaxf(s[2][r], s[3][r]));
        #pragma unroll
        for (int r = 0; r < 4; ++r) {
            #pragma unroll
            for (int off = 1; off < 16; off <<= 1)
                tm[r] = fmaxf(tm[r], __shfl_xor(tm[r], off, 64));
        }
        float corr[4], ps[4];
        #pragma unroll
        for (int r = 0; r < 4; ++r) {
            float mn = fmaxf(m_[r], tm[r]);
            corr[r] = __expf(m_[r] - mn);
            m_[r] = mn;
            ps[r] = 0.f;
        }
        #pragma unroll
        for (int sub = 0; sub < 4; ++sub) {
            #pragma unroll
            for (int r = 0; r < 4; ++r) {
                float p = __expf(s[sub][r] - m_[r]);
                s[sub][r] = p;
                ps[r] += p;
            }
        }
        #pragma unroll
        for (int r = 0; r < 4; ++r) {
            #pragma unroll
            for (int off = 1; off < 16; off <<= 1)
                ps[r] += __shfl_xor(ps[r], off, 64);
            l_[r] = l_[r] * corr[r] + ps[r];
        }
        #pragma unroll
        for (int d = 0; d < 4; ++d) {
            #pragma unroll
            for (int r = 0; r < 4; ++r)
                oacc[d][r] *= corr[r];
        }

        // ---- P -> per-wave LDS (C-layout -> A-layout round trip) ----
        #pragma unroll
        for (int sub = 0; sub < 4; ++sub) {
            #pragma unroll
            for (int r = 0; r < 4; ++r)
                Plds[wave][g * 4 + r][sub * 16 + cc] = f2bf(s[sub][r]);
        }

        // ---- O += P V  (A = P frag, B = V^T frag) ----
        short8 pf[2];
        #pragma unroll
        for (int nc = 0; nc < 2; ++nc)
            pf[nc] = *(short8*)&Plds[wave][cc][nc * 32 + g * 8];
        #pragma unroll
        for (int d = 0; d < 4; ++d) {
            #pragma unroll
            for (int nc = 0; nc < 2; ++nc) {
                short8 vf = *(short8*)&Vt[d * 16 + cc][nc * 32 + g * 8];
                oacc[d] = __builtin_amdgcn_mfma_f32_16x16x32_bf16(pf[nc], vf, oacc[d], 0, 0, 0);
            }
        }
    }

    // ---- epilogue: normalize, depthwise out-proj, store fp32 ----
    #pragma unroll
    for (int r = 0; r < 4; ++r) l_[r] = 1.f / l_[r];
    const int orow0 = qt * QB + wave * 16 + g * 4;
    #pragma unroll
    for (int d = 0; d < 4; ++d) {
        const int ch = h * D_ + d * 16 + cc;
        const float wov = wo[ch], bov = bo[ch];
        #pragma unroll
        for (int r = 0; r < 4; ++r) {
            out[((size_t)(b * N_ + orow0 + r)) * F_ + ch] = oacc[d][r] * l_[r] * wov + bov;
        }
    }
}

extern "C" void kernel_launch(void* const* d_in, const int* in_sizes, int n_in,
                              void* d_out, int out_size, void* d_ws, size_t ws_size,
                              hipStream_t stream) {
    const float* x  = (const float*)d_in[0];
    const float* wq = (const float*)d_in[1];
    const float* bq = (const float*)d_in[2];
    const float* wk = (const float*)d_in[3];
    const float* bk = (const float*)d_in[4];
    const float* wv = (const float*)d_in[5];
    const float* bv = (const float*)d_in[6];
    const float* wo = (const float*)d_in[7];
    const float* bo = (const float*)d_in[8];
    float* out = (float*)d_out;

    dim3 grid(B_ * H_ * (N_ / QB));   // 16*12*16 = 3072 blocks
    dim3 block(256);
    attn_fused<<<grid, block, 0, stream>>>(x, wq, bq, wk, bk, wv, bv, wo, bo, out);
}

// Round 2
// 179.281 us; speedup vs baseline: 1.4717x; 1.4717x over previous
//
#include <hip/hip_runtime.h>
#include <hip/hip_bf16.h>
#include <cstdint>
#include <cstddef>

typedef __attribute__((ext_vector_type(8))) short short8;
typedef __attribute__((ext_vector_type(4))) float f32x4;

static constexpr int B_ = 16, N_ = 1024, F_ = 768, H_ = 12, D_ = 64;
static constexpr int NB = 64, NT = N_ / NB;      // kv tile rows, #tiles
static constexpr int QB = 256;                   // q rows per block (main)
static constexpr float RSCALE = 0.036084391824351615f;               // 1/sqrt(768)
static constexpr float QSCALE = 0.036084391824351615f * 1.4426950408889634f; // * log2(e)

__device__ __forceinline__ short f2bf(float f) {
    return __builtin_bit_cast(short, __float2bfloat16(f));
}

#define GLB(p)  ((const __attribute__((address_space(1))) void*)(p))
#define LDSP(p) ((__attribute__((address_space(3))) void*)(p))

// ---------------------------------------------------------------------------
// Prep: K row-major [bh][t][n][ch], V transposed [bh][t][d][n], bf16,
// 8KB tiles, 16B chunks XOR-swizzled by (row&7) so main-kernel ds_read_b128
// fragment reads are bank-uniform while global_load_lds stays linear.
// ---------------------------------------------------------------------------
__global__ void __launch_bounds__(256) prep_kv(
    const float* __restrict__ x,
    const float* __restrict__ wk, const float* __restrict__ bk,
    const float* __restrict__ wv, const float* __restrict__ bv,
    short* __restrict__ Kt, short* __restrict__ Vt)
{
    const int bid = blockIdx.x;          // = bh*16 + t
    const int t   = bid & 15;
    const int bh  = bid >> 4;
    const int h   = bh % H_, b = bh / H_;
    const int nb  = t * NB;
    const int tid = threadIdx.x;
    short* Ktile = Kt + ((size_t)bid << 12);
    short* Vtile = Vt + ((size_t)bid << 12);

    { // K: thread -> (row n, 16 channels)
        const int n = tid >> 2, sg = tid & 3;
        const float* xr  = x  + ((size_t)(b * N_ + nb + n)) * F_ + h * D_ + sg * 16;
        const float* wkp = wk + h * D_ + sg * 16;
        const float* bkp = bk + h * D_ + sg * 16;
        float xv[16];
        #pragma unroll
        for (int q = 0; q < 4; ++q) *(float4*)&xv[q * 4] = *(const float4*)(xr + q * 4);
        short kb[16];
        #pragma unroll
        for (int i = 0; i < 16; ++i) kb[i] = f2bf(xv[i] * wkp[i] + bkp[i]);
        const int swz = n & 7;
        #pragma unroll
        for (int c2 = 0; c2 < 2; ++c2) {
            const int c = sg * 2 + c2;
            *(short8*)&Ktile[n * 64 + ((c ^ swz) << 3)] = *(short8*)&kb[c2 * 8];
        }
    }
    { // V^T: thread -> (channel d, 16 n values); lanes span d => coalesced reads
        const int d = tid & 63, ng = tid >> 6;
        const float wvd = wv[h * D_ + d], bvd = bv[h * D_ + d];
        const float* xc = x + ((size_t)(b * N_ + nb + ng * 16)) * F_ + h * D_ + d;
        short vb[16];
        #pragma unroll
        for (int j = 0; j < 16; ++j) vb[j] = f2bf(xc[(size_t)j * F_] * wvd + bvd);
        const int swz = d & 7;
        #pragma unroll
        for (int c2 = 0; c2 < 2; ++c2) {
            const int c = ng * 2 + c2;
            *(short8*)&Vtile[d * 64 + ((c ^ swz) << 3)] = *(short8*)&vb[c2 * 8];
        }
    }
}

// ---------------------------------------------------------------------------
// Main: 8 waves x 32 q-rows, dbuf LDS K/V via global_load_lds, flash softmax
// ---------------------------------------------------------------------------
__global__ void __launch_bounds__(512, 4) attn_main(
    const float* __restrict__ x,
    const float* __restrict__ wq, const float* __restrict__ bq,
    const short* __restrict__ Kt, const short* __restrict__ Vt,
    const float* __restrict__ wo, const float* __restrict__ bo,
    float* __restrict__ out)
{
    __shared__ short KV[2][2][4096];     // [dbuf][K/V][64 rows x 64 ch swizzled]
    __shared__ short Pl[8][16][72];      // per-wave P tile, padded rows (144B)

    const int tid  = threadIdx.x;
    const int w    = tid >> 6, lane = tid & 63;
    const int g    = lane >> 4, cc = lane & 15;

    const int orig = blockIdx.x;
    const int sb   = (orig & 7) * 96 + (orig >> 3);  // XCD swizzle (768%8==0, bijective)
    const int qt   = sb & 3, bh = sb >> 2;
    const int h    = bh % H_, b = bh / H_;

    // ---- Q fragments (projected in-register, once; QSCALE folds 1/sqrt(F)*log2e) ----
    short8 qf[2][2];
    const int qrow0 = qt * QB + w * 32;
    #pragma unroll
    for (int mt = 0; mt < 2; ++mt) {
        const float* xq = x + ((size_t)(b * N_ + qrow0 + mt * 16 + cc)) * F_ + h * D_;
        #pragma unroll
        for (int kc = 0; kc < 2; ++kc) {
            const int dd = kc * 32 + g * 8;
            float4 a0 = *(const float4*)(xq + dd);
            float4 a1 = *(const float4*)(xq + dd + 4);
            const float* wqp = wq + h * D_ + dd;
            const float* bqp = bq + h * D_ + dd;
            float qa[8] = {a0.x,a0.y,a0.z,a0.w,a1.x,a1.y,a1.z,a1.w};
            #pragma unroll
            for (int i = 0; i < 8; ++i)
                qf[mt][kc][i] = f2bf((qa[i] * wqp[i] + bqp[i]) * QSCALE);
        }
    }

    float m_[2][4], l_[2][4];
    f32x4 oacc[2][4];
    #pragma unroll
    for (int mt = 0; mt < 2; ++mt)
        #pragma unroll
        for (int r = 0; r < 4; ++r) {
            m_[mt][r] = -INFINITY; l_[mt][r] = 0.f;
            oacc[mt][r] = (f32x4){0.f, 0.f, 0.f, 0.f};
        }

    const int swz = cc & 7;
    const int koff0 = ((g     ^ swz) << 3);   // chunk offset (elems), kc/nc = 0
    const int koff1 = (((4+g) ^ swz) << 3);   // kc/nc = 1

    const size_t base = ((size_t)bh) * (NT * 4096);

    auto stage = [&](int buf, int tt) {
        const short* ks = Kt + base + ((size_t)tt << 12) + tid * 8;
        const short* vs = Vt + base + ((size_t)tt << 12) + tid * 8;
        __builtin_amdgcn_global_load_lds(GLB(ks), LDSP(&KV[buf][0][w * 512]), 16, 0, 0);
        __builtin_amdgcn_global_load_lds(GLB(vs), LDSP(&KV[buf][1][w * 512]), 16, 0, 0);
    };

    stage(0, 0);
    __syncthreads();

    for (int t = 0; t < NT; ++t) {
        const int cur = t & 1;
        if (t + 1 < NT) stage(cur ^ 1, t + 1);   // issue early, drain at barrier
        const short* Kb = KV[cur][0];
        const short* Vb = KV[cur][1];

        // ---- S = Q K^T ----
        f32x4 sAcc[2][4];
        #pragma unroll
        for (int mt = 0; mt < 2; ++mt)
            #pragma unroll
            for (int sub = 0; sub < 4; ++sub) sAcc[mt][sub] = (f32x4){0.f,0.f,0.f,0.f};
        #pragma unroll
        for (int sub = 0; sub < 4; ++sub) {
            const int rb = (sub * 16 + cc) * 64;
            short8 kf0 = *(const short8*)&Kb[rb + koff0];
            short8 kf1 = *(const short8*)&Kb[rb + koff1];
            sAcc[0][sub] = __builtin_amdgcn_mfma_f32_16x16x32_bf16(qf[0][0], kf0, sAcc[0][sub], 0,0,0);
            sAcc[1][sub] = __builtin_amdgcn_mfma_f32_16x16x32_bf16(qf[1][0], kf0, sAcc[1][sub], 0,0,0);
            sAcc[0][sub] = __builtin_amdgcn_mfma_f32_16x16x32_bf16(qf[0][1], kf1, sAcc[0][sub], 0,0,0);
            sAcc[1][sub] = __builtin_amdgcn_mfma_f32_16x16x32_bf16(qf[1][1], kf1, sAcc[1][sub], 0,0,0);
        }

        // ---- online softmax + P pack + PV A-frags (per M-tile) ----
        short8 pf[2][2];
        #pragma unroll
        for (int mt = 0; mt < 2; ++mt) {
            float tm[4], corr[4], ps[4];
            #pragma unroll
            for (int r = 0; r < 4; ++r)
                tm[r] = fmaxf(fmaxf(sAcc[mt][0][r], sAcc[mt][1][r]),
                              fmaxf(sAcc[mt][2][r], sAcc[mt][3][r]));
            #pragma unroll
            for (int r = 0; r < 4; ++r) {
                #pragma unroll
                for (int off = 1; off < 16; off <<= 1)
                    tm[r] = fmaxf(tm[r], __shfl_xor(tm[r], off, 64));
                const float mn = fmaxf(m_[mt][r], tm[r]);
                corr[r] = exp2f(m_[mt][r] - mn);
                m_[mt][r] = mn;
                ps[r] = 0.f;
            }
            #pragma unroll
            for (int sub = 0; sub < 4; ++sub) {
                #pragma unroll
                for (int r = 0; r < 4; ++r) {
                    const float p = exp2f(sAcc[mt][sub][r] - m_[mt][r]);
                    ps[r] += p;
                    Pl[w][g * 4 + r][sub * 16 + cc] = f2bf(p);
                }
            }
            #pragma unroll
            for (int r = 0; r < 4; ++r) {
                #pragma unroll
                for (int off = 1; off < 16; off <<= 1)
                    ps[r] += __shfl_xor(ps[r], off, 64);
                l_[mt][r] = l_[mt][r] * corr[r] + ps[r];
            }
            #pragma unroll
            for (int ds = 0; ds < 4; ++ds)
                #pragma unroll
                for (int r = 0; r < 4; ++r)
                    oacc[mt][ds][r] *= corr[r];
            // read this M-tile's A-fragments back before next mt overwrites Pl[w]
            #pragma unroll
            for (int nc = 0; nc < 2; ++nc)
                pf[mt][nc] = *(const short8*)&Pl[w][cc][nc * 32 + g * 8];
        }

        // ---- O += P V ----
        #pragma unroll
        for (int ds = 0; ds < 4; ++ds) {
            const int rb = (ds * 16 + cc) * 64;
            short8 vf0 = *(const short8*)&Vb[rb + koff0];
            short8 vf1 = *(const short8*)&Vb[rb + koff1];
            oacc[0][ds] = __builtin_amdgcn_mfma_f32_16x16x32_bf16(pf[0][0], vf0, oacc[0][ds], 0,0,0);
            oacc[1][ds] = __builtin_amdgcn_mfma_f32_16x16x32_bf16(pf[1][0], vf0, oacc[1][ds], 0,0,0);
            oacc[0][ds] = __builtin_amdgcn_mfma_f32_16x16x32_bf16(pf[0][1], vf1, oacc[0][ds], 0,0,0);
            oacc[1][ds] = __builtin_amdgcn_mfma_f32_16x16x32_bf16(pf[1][1], vf1, oacc[1][ds], 0,0,0);
        }

        __syncthreads();   // drains next-tile global_load_lds + guards dbuf reuse
    }

    // ---- epilogue ----
    #pragma unroll
    for (int mt = 0; mt < 2; ++mt) {
        float inv[4];
        #pragma unroll
        for (int r = 0; r < 4; ++r) inv[r] = 1.f / l_[mt][r];
        const int orow0 = qrow0 + mt * 16 + g * 4;
        #pragma unroll
        for (int ds = 0; ds < 4; ++ds) {
            const int ch = h * D_ + ds * 16 + cc;
            const float wov = wo[ch], bov = bo[ch];
            #pragma unroll
            for (int r = 0; r < 4; ++r)
                out[((size_t)(b * N_ + orow0 + r)) * F_ + ch] = oacc[mt][ds][r] * inv[r] * wov + bov;
        }
    }
}

// ---------------------------------------------------------------------------
// Fallback (round-1 kernel) if workspace is too small
// ---------------------------------------------------------------------------
__global__ void __launch_bounds__(256) attn_fused(
    const float* __restrict__ x,
    const float* __restrict__ wq, const float* __restrict__ bq,
    const float* __restrict__ wk, const float* __restrict__ bk,
    const float* __restrict__ wv, const float* __restrict__ bv,
    const float* __restrict__ wo, const float* __restrict__ bo,
    float* __restrict__ out)
{
    __shared__ short Klds[64][72];
    __shared__ short Vt[64][72];
    __shared__ short Plds[4][16][72];

    const int tid = threadIdx.x;
    const int wave = tid >> 6, lane = tid & 63;
    const int g = lane >> 4, cc = lane & 15;
    const int bid = blockIdx.x;
    const int qt = bid & 15, t1 = bid >> 4;
    const int h = t1 % H_, b = t1 / H_;

    const int qrow = qt * 64 + wave * 16 + cc;
    const float* xq = x + ((size_t)(b * N_ + qrow)) * F_ + h * D_;
    short8 qf[2];
    #pragma unroll
    for (int kc = 0; kc < 2; ++kc) {
        const int dd = kc * 32 + g * 8;
        float4 a0 = *(const float4*)(xq + dd);
        float4 a1 = *(const float4*)(xq + dd + 4);
        float qa[8] = {a0.x,a0.y,a0.z,a0.w,a1.x,a1.y,a1.z,a1.w};
        #pragma unroll
        for (int i = 0; i < 8; ++i) {
            const int ch = h * D_ + dd + i;
            qf[kc][i] = f2bf((qa[i] * wq[ch] + bq[ch]) * RSCALE);
        }
    }
    const int srow = tid >> 2, seg = tid & 3;
    const int cb = h * D_ + seg * 16;
    float m_[4], l_[4];
    f32x4 oacc[4];
    #pragma unroll
    for (int r = 0; r < 4; ++r) { m_[r] = -INFINITY; l_[r] = 0.f; oacc[r] = (f32x4){0,0,0,0}; }

    for (int nb = 0; nb < N_; nb += 64) {
        __syncthreads();
        {
            const float* xr = x + ((size_t)(b * N_ + nb + srow)) * F_ + cb;
            float4 x0 = *(const float4*)(xr + 0), x1 = *(const float4*)(xr + 4);
            float4 x2 = *(const float4*)(xr + 8), x3 = *(const float4*)(xr + 12);
            float xf[16] = {x0.x,x0.y,x0.z,x0.w,x1.x,x1.y,x1.z,x1.w,
                            x2.x,x2.y,x2.z,x2.w,x3.x,x3.y,x3.z,x3.w};
            short8 k0, k1;
            #pragma unroll
            for (int i = 0; i < 8; ++i) {
                k0[i] = f2bf(xf[i] * wk[cb+i] + bk[cb+i]);
                k1[i] = f2bf(xf[i+8] * wk[cb+i+8] + bk[cb+i+8]);
            }
            *(short8*)&Klds[srow][seg*16] = k0;
            *(short8*)&Klds[srow][seg*16+8] = k1;
            #pragma unroll
            for (int i = 0; i < 16; ++i)
                Vt[seg*16+i][srow] = f2bf(xf[i] * wv[cb+i] + bv[cb+i]);
        }
        __syncthreads();
        f32x4 s[4];
        #pragma unroll
        for (int sub = 0; sub < 4; ++sub) {
            f32x4 acc = (f32x4){0,0,0,0};
            #pragma unroll
            for (int kc = 0; kc < 2; ++kc) {
                short8 kf = *(short8*)&Klds[sub*16+cc][kc*32+g*8];
                acc = __builtin_amdgcn_mfma_f32_16x16x32_bf16(qf[kc], kf, acc, 0,0,0);
            }
            s[sub] = acc;
        }
        float tm[4];
        #pragma unroll
        for (int r = 0; r < 4; ++r)
            tm[r] = fmaxf(fmaxf(s[0][r], s[1][r]), fmaxf(s[2][r], s[3][r]));
        #pragma unroll
        for (int r = 0; r < 4; ++r)
            #pragma unroll
            for (int off = 1; off < 16; off <<= 1)
                tm[r] = fmaxf(tm[r], __shfl_xor(tm[r], off, 64));
        float corr[4], ps[4];
        #pragma unroll
        for (int r = 0; r < 4; ++r) {
            float mn = fmaxf(m_[r], tm[r]);
            corr[r] = __expf(m_[r] - mn);
            m_[r] = mn; ps[r] = 0.f;
        }
        #pragma unroll
        for (int sub = 0; sub < 4; ++sub)
            #pragma unroll
            for (int r = 0; r < 4; ++r) {
                float p = __expf(s[sub][r] - m_[r]);
                s[sub][r] = p; ps[r] += p;
            }
        #pragma unroll
        for (int r = 0; r < 4; ++r) {
            #pragma unroll
            for (int off = 1; off < 16; off <<= 1)
                ps[r] += __shfl_xor(ps[r], off, 64);
            l_[r] = l_[r] * corr[r] + ps[r];
        }
        #pragma unroll
        for (int d = 0; d < 4; ++d)
            #pragma unroll
            for (int r = 0; r < 4; ++r) oacc[d][r] *= corr[r];
        #pragma unroll
        for (int sub = 0; sub < 4; ++sub)
            #pragma unroll
            for (int r = 0; r < 4; ++r)
                Plds[wave][g*4+r][sub*16+cc] = f2bf(s[sub][r]);
        short8 pf[2];
        #pragma unroll
        for (int nc = 0; nc < 2; ++nc)
            pf[nc] = *(short8*)&Plds[wave][cc][nc*32+g*8];
        #pragma unroll
        for (int d = 0; d < 4; ++d)
            #pragma unroll
            for (int nc = 0; nc < 2; ++nc) {
                short8 vf = *(short8*)&Vt[d*16+cc][nc*32+g*8];
                oacc[d] = __builtin_amdgcn_mfma_f32_16x16x32_bf16(pf[nc], vf, oacc[d], 0,0,0);
            }
    }
    #pragma unroll
    for (int r = 0; r < 4; ++r) l_[r] = 1.f / l_[r];
    const int orow0 = qt * 64 + wave * 16 + g * 4;
    #pragma unroll
    for (int d = 0; d < 4; ++d) {
        const int ch = h * D_ + d * 16 + cc;
        const float wov = wo[ch], bov = bo[ch];
        #pragma unroll
        for (int r = 0; r < 4; ++r)
            out[((size_t)(b * N_ + orow0 + r)) * F_ + ch] = oacc[d][r] * l_[r] * wov + bov;
    }
}

extern "C" void kernel_launch(void* const* d_in, const int* in_sizes, int n_in,
                              void* d_out, int out_size, void* d_ws, size_t ws_size,
                              hipStream_t stream) {
    const float* x  = (const float*)d_in[0];
    const float* wq = (const float*)d_in[1];
    const float* bq = (const float*)d_in[2];
    const float* wk = (const float*)d_in[3];
    const float* bk = (const float*)d_in[4];
    const float* wv = (const float*)d_in[5];
    const float* bv = (const float*)d_in[6];
    const float* wo = (const float*)d_in[7];
    const float* bo = (const float*)d_in[8];
    float* out = (float*)d_out;

    const size_t elems = (size_t)B_ * H_ * N_ * D_;      // 12,582,912
    const size_t need  = elems * 2 * 2;                  // K + V, bf16
    if (ws_size >= need) {
        short* Ktw = (short*)d_ws;
        short* Vtw = Ktw + elems;
        prep_kv<<<dim3(B_ * H_ * NT), dim3(256), 0, stream>>>(x, wk, bk, wv, bv, Ktw, Vtw);
        attn_main<<<dim3(B_ * H_ * (N_ / QB)), dim3(512), 0, stream>>>(
            x, wq, bq, Ktw, Vtw, wo, bo, out);
    } else {
        attn_fused<<<dim3(B_ * H_ * (N_ / 64)), dim3(256), 0, stream>>>(
            x, wq, bq, wk, bk, wv, bv, wo, bo, out);
    }
}

// Round 5
// 114.300 us; speedup vs baseline: 2.3084x; 1.5685x over previous
//
#include <hip/hip_runtime.h>
#include <hip/hip_bf16.h>
#include <cstdint>
#include <cstddef>

typedef __attribute__((ext_vector_type(8))) short short8;
typedef __attribute__((ext_vector_type(4))) short short4v;
typedef __attribute__((ext_vector_type(4))) float f32x4;
typedef __attribute__((ext_vector_type(16))) float f32x16;
typedef __attribute__((ext_vector_type(4))) unsigned int uint4v;

static constexpr int B_ = 16, N_ = 1024, F_ = 768, H_ = 12, D_ = 64;
static constexpr int NB = 64, NT = N_ / NB;      // kv tile rows, #tiles
static constexpr int QB = 256;                   // q rows per block (main)
static constexpr float RSCALE = 0.036084391824351615f;               // 1/sqrt(768)
static constexpr float QSCALE = 0.036084391824351615f * 1.4426950408889634f; // * log2(e)
static constexpr float DEFER_THR = 8.0f;         // exp2-domain defer-max threshold

__device__ __forceinline__ short f2bf(float f) {
    return __builtin_bit_cast(short, __float2bfloat16(f));
}
__device__ __forceinline__ unsigned cvtpk(float lo, float hi) {
    unsigned r;
    asm("v_cvt_pk_bf16_f32 %0, %1, %2" : "=v"(r) : "v"(lo), "v"(hi));
    return r;
}

#define GLB(p)  ((const __attribute__((address_space(1))) void*)(p))
#define LDSP(p) ((__attribute__((address_space(3))) void*)(p))

// ---------------------------------------------------------------------------
// Prep: K row-major [bh][t][n][ch], V transposed [bh][t][d][n], bf16,
// 8KB tiles, 16B chunks XOR-swizzled by (row&7).
// ---------------------------------------------------------------------------
__global__ void __launch_bounds__(256) prep_kv(
    const float* __restrict__ x,
    const float* __restrict__ wk, const float* __restrict__ bk,
    const float* __restrict__ wv, const float* __restrict__ bv,
    short* __restrict__ Kt, short* __restrict__ Vt)
{
    const int bid = blockIdx.x;          // = bh*16 + t
    const int t   = bid & 15;
    const int bh  = bid >> 4;
    const int h   = bh % H_, b = bh / H_;
    const int nb  = t * NB;
    const int tid = threadIdx.x;
    short* Ktile = Kt + ((size_t)bid << 12);
    short* Vtile = Vt + ((size_t)bid << 12);

    { // K: thread -> (row n, 16 channels)
        const int n = tid >> 2, sg = tid & 3;
        const float* xr  = x  + ((size_t)(b * N_ + nb + n)) * F_ + h * D_ + sg * 16;
        const float* wkp = wk + h * D_ + sg * 16;
        const float* bkp = bk + h * D_ + sg * 16;
        float xv[16];
        #pragma unroll
        for (int q = 0; q < 4; ++q) *(float4*)&xv[q * 4] = *(const float4*)(xr + q * 4);
        short kb[16];
        #pragma unroll
        for (int i = 0; i < 16; ++i) kb[i] = f2bf(xv[i] * wkp[i] + bkp[i]);
        const int swz = n & 7;
        #pragma unroll
        for (int c2 = 0; c2 < 2; ++c2) {
            const int c = sg * 2 + c2;
            *(short8*)&Ktile[n * 64 + ((c ^ swz) << 3)] = *(short8*)&kb[c2 * 8];
        }
    }
    { // V^T: thread -> (channel d, 16 n values)
        const int d = tid & 63, ng = tid >> 6;
        const float wvd = wv[h * D_ + d], bvd = bv[h * D_ + d];
        const float* xc = x + ((size_t)(b * N_ + nb + ng * 16)) * F_ + h * D_ + d;
        short vb[16];
        #pragma unroll
        for (int j = 0; j < 16; ++j) vb[j] = f2bf(xc[(size_t)j * F_] * wvd + bvd);
        const int swz = d & 7;
        #pragma unroll
        for (int c2 = 0; c2 < 2; ++c2) {
            const int c = ng * 2 + c2;
            *(short8*)&Vtile[d * 64 + ((c ^ swz) << 3)] = *(short8*)&vb[c2 * 8];
        }
    }
}

// ---------------------------------------------------------------------------
// Main: 8 waves x 32 q-rows, 32x32x16 MFMA, swapped QK^T (S^T), O^T accum.
// P^T B-fragment is built as a PLAIN register-order cvt_pk pack; the V^T
// A-fragment is loaded with the SAME (hi, elem)->n placement function
// (two b64 halves: n = s*16+4hi+0..3 and s*16+8+4hi+0..3), so PV is
// consistent for ANY hardware k-map (only A/B symmetry assumed).
// Cross-half reduces use __shfl_xor(.,32) - unambiguous semantics.
// ---------------------------------------------------------------------------
__global__ void __launch_bounds__(512, 4) attn_main(
    const float* __restrict__ x,
    const float* __restrict__ wq, const float* __restrict__ bq,
    const short* __restrict__ Kt, const short* __restrict__ Vt,
    const float* __restrict__ wo, const float* __restrict__ bo,
    float* __restrict__ out)
{
    __shared__ short KV[2][2][4096];     // [dbuf][K/V][64 rows x 64 ch swizzled]

    const int tid  = threadIdx.x;
    const int w    = tid >> 6, lane = tid & 63;
    const int q32  = lane & 31, hi = lane >> 5;

    const int orig = blockIdx.x;
    const int sb   = (orig & 7) * 96 + (orig >> 3);  // XCD swizzle (768%8==0)
    const int qt   = sb & 3, bh = sb >> 2;
    const int h    = bh % H_, b = bh / H_;
    const int qrow0 = qt * QB + w * 32;
    const int qa    = qrow0 + q32;                   // this lane's q row

    // ---- Q as B-fragments (contiguous map, matching K's A-load) ----
    short8 qf[4];
    {
        const float* xq = x + ((size_t)(b * N_ + qa)) * F_ + h * D_;
        #pragma unroll
        for (int s = 0; s < 4; ++s) {
            const int ch0 = s * 16 + hi * 8;
            float4 a0 = *(const float4*)(xq + ch0);
            float4 a1 = *(const float4*)(xq + ch0 + 4);
            const float* wqp = wq + h * D_ + ch0;
            const float* bqp = bq + h * D_ + ch0;
            float q8[8] = {a0.x,a0.y,a0.z,a0.w,a1.x,a1.y,a1.z,a1.w};
            uint4v u;
            #pragma unroll
            for (int j = 0; j < 4; ++j) {
                const float lo = (q8[2*j]   * wqp[2*j]   + bqp[2*j])   * QSCALE;
                const float hf = (q8[2*j+1] * wqp[2*j+1] + bqp[2*j+1]) * QSCALE;
                u[j] = cvtpk(lo, hf);
            }
            qf[s] = __builtin_bit_cast(short8, u);
        }
    }

    // LDS fragment chunk offsets (elems); row-swizzle = q32&7 (rows differ by 32)
    const int swz = q32 & 7;
    int coff[4];
    #pragma unroll
    for (int s = 0; s < 4; ++s) coff[s] = (((s * 2 + hi) ^ swz) << 3);
    const int rA = q32 * 64;           // row base, subtile 0
    const int rB = (32 + q32) * 64;    // row base, subtile 1

    float m_ = -INFINITY, l_ = 0.f;
    f32x16 oA, oB;
    #pragma unroll
    for (int r = 0; r < 16; ++r) { oA[r] = 0.f; oB[r] = 0.f; }

    const size_t base = ((size_t)bh) * (NT * 4096);
    auto stage = [&](int buf, int tt) {
        const short* ks = Kt + base + ((size_t)tt << 12) + tid * 8;
        const short* vs = Vt + base + ((size_t)tt << 12) + tid * 8;
        __builtin_amdgcn_global_load_lds(GLB(ks), LDSP(&KV[buf][0][w * 512]), 16, 0, 0);
        __builtin_amdgcn_global_load_lds(GLB(vs), LDSP(&KV[buf][1][w * 512]), 16, 0, 0);
    };

    stage(0, 0);

    for (int t = 0; t < NT; ++t) {
        const int cur = t & 1;
        __syncthreads();                      // drains tile-t loads (issued 1 tile ago)
        if (t + 1 < NT) stage(cur ^ 1, t + 1);   // overlaps with this tile's compute
        const short* Kb = &KV[cur][0][0];
        const short* Vb = &KV[cur][1][0];

        // ---- S^T = K Q^T : lane holds S[k][q=q32] for 32 k-values ----
        f32x16 sA, sB;
        #pragma unroll
        for (int r = 0; r < 16; ++r) { sA[r] = 0.f; sB[r] = 0.f; }
        __builtin_amdgcn_s_setprio(1);
        #pragma unroll
        for (int s = 0; s < 4; ++s) {
            short8 k0 = *(const short8*)&Kb[rA + coff[s]];
            short8 k1 = *(const short8*)&Kb[rB + coff[s]];
            sA = __builtin_amdgcn_mfma_f32_32x32x16_bf16(k0, qf[s], sA, 0, 0, 0);
            sB = __builtin_amdgcn_mfma_f32_32x32x16_bf16(k1, qf[s], sB, 0, 0, 0);
        }
        __builtin_amdgcn_s_setprio(0);

        // ---- row max (lane-local + one cross-half shfl) ----
        float tm = sA[0];
        #pragma unroll
        for (int r = 1; r < 16; ++r) tm = fmaxf(tm, sA[r]);
        #pragma unroll
        for (int r = 0; r < 16; ++r) tm = fmaxf(tm, sB[r]);
        tm = fmaxf(tm, __shfl_xor(tm, 32, 64));

        // ---- defer-max: rescale only when max grew past threshold ----
        if (!__all(tm - m_ <= DEFER_THR)) {
            const float mn = fmaxf(m_, tm);
            const float corr = exp2f(m_ - mn);   // -inf -> 0 first tile
            l_ *= corr;
            #pragma unroll
            for (int r = 0; r < 16; ++r) { oA[r] *= corr; oB[r] *= corr; }
            m_ = mn;
        }

        // ---- P = exp2(S - m), row sum ----
        float ps = 0.f;
        #pragma unroll
        for (int r = 0; r < 16; ++r) { sA[r] = exp2f(sA[r] - m_); ps += sA[r]; }
        #pragma unroll
        for (int r = 0; r < 16; ++r) { sB[r] = exp2f(sB[r] - m_); ps += sB[r]; }
        ps += __shfl_xor(ps, 32, 64);
        l_ += ps;

        // ---- pack P^T B-frags: plain register order, 16 cvt_pk, no shuffles ----
        short8 pf[4];
        {
            uint4v u0, u1, u2, u3;
            u0[0] = cvtpk(sA[0],  sA[1]);  u0[1] = cvtpk(sA[2],  sA[3]);
            u0[2] = cvtpk(sA[4],  sA[5]);  u0[3] = cvtpk(sA[6],  sA[7]);
            u1[0] = cvtpk(sA[8],  sA[9]);  u1[1] = cvtpk(sA[10], sA[11]);
            u1[2] = cvtpk(sA[12], sA[13]); u1[3] = cvtpk(sA[14], sA[15]);
            u2[0] = cvtpk(sB[0],  sB[1]);  u2[1] = cvtpk(sB[2],  sB[3]);
            u2[2] = cvtpk(sB[4],  sB[5]);  u2[3] = cvtpk(sB[6],  sB[7]);
            u3[0] = cvtpk(sB[8],  sB[9]);  u3[1] = cvtpk(sB[10], sB[11]);
            u3[2] = cvtpk(sB[12], sB[13]); u3[3] = cvtpk(sB[14], sB[15]);
            pf[0] = __builtin_bit_cast(short8, u0);
            pf[1] = __builtin_bit_cast(short8, u1);
            pf[2] = __builtin_bit_cast(short8, u2);
            pf[3] = __builtin_bit_cast(short8, u3);
        }

        // ---- O^T += V^T P^T ; V loaded with P's placement function:
        //      elems 0-3 <- n = s*16+4hi+0..3, elems 4-7 <- n = s*16+8+4hi+0..3
        __builtin_amdgcn_s_setprio(1);
        #pragma unroll
        for (int s = 0; s < 4; ++s) {
            const int cLo = ((2*s    ) ^ swz) << 3;
            const int cHi = ((2*s + 1) ^ swz) << 3;
            short4v aLo = *(const short4v*)&Vb[rA + cLo + 4*hi];
            short4v aHi = *(const short4v*)&Vb[rA + cHi + 4*hi];
            short4v bLo = *(const short4v*)&Vb[rB + cLo + 4*hi];
            short4v bHi = *(const short4v*)&Vb[rB + cHi + 4*hi];
            short8 v0 = {aLo[0],aLo[1],aLo[2],aLo[3], aHi[0],aHi[1],aHi[2],aHi[3]};
            short8 v1 = {bLo[0],bLo[1],bLo[2],bLo[3], bHi[0],bHi[1],bHi[2],bHi[3]};
            oA = __builtin_amdgcn_mfma_f32_32x32x16_bf16(v0, pf[s], oA, 0, 0, 0);
            oB = __builtin_amdgcn_mfma_f32_32x32x16_bf16(v1, pf[s], oB, 0, 0, 0);
        }
        __builtin_amdgcn_s_setprio(0);
    }

    // ---- epilogue: O^T[d][q=q32]; reg 4j+i -> d = dsb*32 + 8j + 4hi + i ----
    const float invl = 1.f / l_;
    float* orow = out + ((size_t)(b * N_ + qa)) * F_;
    #pragma unroll
    for (int dsb = 0; dsb < 2; ++dsb) {
        #pragma unroll
        for (int j = 0; j < 4; ++j) {
            const int ch = h * D_ + dsb * 32 + 8 * j + 4 * hi;
            float4 wv = *(const float4*)(wo + ch);
            float4 bv = *(const float4*)(bo + ch);
            float4 o4;
            if (dsb == 0) {
                o4.x = oA[4*j+0] * invl * wv.x + bv.x;
                o4.y = oA[4*j+1] * invl * wv.y + bv.y;
                o4.z = oA[4*j+2] * invl * wv.z + bv.z;
                o4.w = oA[4*j+3] * invl * wv.w + bv.w;
            } else {
                o4.x = oB[4*j+0] * invl * wv.x + bv.x;
                o4.y = oB[4*j+1] * invl * wv.y + bv.y;
                o4.z = oB[4*j+2] * invl * wv.z + bv.z;
                o4.w = oB[4*j+3] * invl * wv.w + bv.w;
            }
            *(float4*)(orow + ch) = o4;
        }
    }
}

// ---------------------------------------------------------------------------
// Fallback (round-1 kernel) if workspace is too small
// ---------------------------------------------------------------------------
__global__ void __launch_bounds__(256) attn_fused(
    const float* __restrict__ x,
    const float* __restrict__ wq, const float* __restrict__ bq,
    const float* __restrict__ wk, const float* __restrict__ bk,
    const float* __restrict__ wv, const float* __restrict__ bv,
    const float* __restrict__ wo, const float* __restrict__ bo,
    float* __restrict__ out)
{
    __shared__ short Klds[64][72];
    __shared__ short Vt[64][72];
    __shared__ short Plds[4][16][72];

    const int tid = threadIdx.x;
    const int wave = tid >> 6, lane = tid & 63;
    const int g = lane >> 4, cc = lane & 15;
    const int bid = blockIdx.x;
    const int qt = bid & 15, t1 = bid >> 4;
    const int h = t1 % H_, b = t1 / H_;

    const int qrow = qt * 64 + wave * 16 + cc;
    const float* xq = x + ((size_t)(b * N_ + qrow)) * F_ + h * D_;
    short8 qf[2];
    #pragma unroll
    for (int kc = 0; kc < 2; ++kc) {
        const int dd = kc * 32 + g * 8;
        float4 a0 = *(const float4*)(xq + dd);
        float4 a1 = *(const float4*)(xq + dd + 4);
        float qa[8] = {a0.x,a0.y,a0.z,a0.w,a1.x,a1.y,a1.z,a1.w};
        #pragma unroll
        for (int i = 0; i < 8; ++i) {
            const int ch = h * D_ + dd + i;
            qf[kc][i] = f2bf((qa[i] * wq[ch] + bq[ch]) * RSCALE);
        }
    }
    const int srow = tid >> 2, seg = tid & 3;
    const int cb = h * D_ + seg * 16;
    float m_[4], l_[4];
    f32x4 oacc[4];
    #pragma unroll
    for (int r = 0; r < 4; ++r) { m_[r] = -INFINITY; l_[r] = 0.f; oacc[r] = (f32x4){0,0,0,0}; }

    for (int nb = 0; nb < N_; nb += 64) {
        __syncthreads();
        {
            const float* xr = x + ((size_t)(b * N_ + nb + srow)) * F_ + cb;
            float4 x0 = *(const float4*)(xr + 0), x1 = *(const float4*)(xr + 4);
            float4 x2 = *(const float4*)(xr + 8), x3 = *(const float4*)(xr + 12);
            float xf[16] = {x0.x,x0.y,x0.z,x0.w,x1.x,x1.y,x1.z,x1.w,
                            x2.x,x2.y,x2.z,x2.w,x3.x,x3.y,x3.z,x3.w};
            short8 k0, k1;
            #pragma unroll
            for (int i = 0; i < 8; ++i) {
                k0[i] = f2bf(xf[i] * wk[cb+i] + bk[cb+i]);
                k1[i] = f2bf(xf[i+8] * wk[cb+i+8] + bk[cb+i+8]);
            }
            *(short8*)&Klds[srow][seg*16] = k0;
            *(short8*)&Klds[srow][seg*16+8] = k1;
            #pragma unroll
            for (int i = 0; i < 16; ++i)
                Vt[seg*16+i][srow] = f2bf(xf[i] * wv[cb+i] + bv[cb+i]);
        }
        __syncthreads();
        f32x4 s[4];
        #pragma unroll
        for (int sub = 0; sub < 4; ++sub) {
            f32x4 acc = (f32x4){0,0,0,0};
            #pragma unroll
            for (int kc = 0; kc < 2; ++kc) {
                short8 kf = *(short8*)&Klds[sub*16+cc][kc*32+g*8];
                acc = __builtin_amdgcn_mfma_f32_16x16x32_bf16(qf[kc], kf, acc, 0,0,0);
            }
            s[sub] = acc;
        }
        float tm[4];
        #pragma unroll
        for (int r = 0; r < 4; ++r)
            tm[r] = fmaxf(fmaxf(s[0][r], s[1][r]), fmaxf(s[2][r], s[3][r]));
        #pragma unroll
        for (int r = 0; r < 4; ++r)
            #pragma unroll
            for (int off = 1; off < 16; off <<= 1)
                tm[r] = fmaxf(tm[r], __shfl_xor(tm[r], off, 64));
        float corr[4], ps[4];
        #pragma unroll
        for (int r = 0; r < 4; ++r) {
            float mn = fmaxf(m_[r], tm[r]);
            corr[r] = __expf(m_[r] - mn);
            m_[r] = mn; ps[r] = 0.f;
        }
        #pragma unroll
        for (int sub = 0; sub < 4; ++sub)
            #pragma unroll
            for (int r = 0; r < 4; ++r) {
                float p = __expf(s[sub][r] - m_[r]);
                s[sub][r] = p; ps[r] += p;
            }
        #pragma unroll
        for (int r = 0; r < 4; ++r) {
            #pragma unroll
            for (int off = 1; off < 16; off <<= 1)
                ps[r] += __shfl_xor(ps[r], off, 64);
            l_[r] = l_[r] * corr[r] + ps[r];
        }
        #pragma unroll
        for (int d = 0; d < 4; ++d)
            #pragma unroll
            for (int r = 0; r < 4; ++r) oacc[d][r] *= corr[r];
        #pragma unroll
        for (int sub = 0; sub < 4; ++sub)
            #pragma unroll
            for (int r = 0; r < 4; ++r)
                Plds[wave][g*4+r][sub*16+cc] = f2bf(s[sub][r]);
        short8 pf[2];
        #pragma unroll
        for (int nc = 0; nc < 2; ++nc)
            pf[nc] = *(short8*)&Plds[wave][cc][nc*32+g*8];
        #pragma unroll
        for (int d = 0; d < 4; ++d)
            #pragma unroll
            for (int nc = 0; nc < 2; ++nc) {
                short8 vf = *(short8*)&Vt[d*16+cc][nc*32+g*8];
                oacc[d] = __builtin_amdgcn_mfma_f32_16x16x32_bf16(pf[nc], vf, oacc[d], 0,0,0);
            }
    }
    #pragma unroll
    for (int r = 0; r < 4; ++r) l_[r] = 1.f / l_[r];
    const int orow0 = qt * 64 + wave * 16 + g * 4;
    #pragma unroll
    for (int d = 0; d < 4; ++d) {
        const int ch = h * D_ + d * 16 + cc;
        const float wov = wo[ch], bov = bo[ch];
        #pragma unroll
        for (int r = 0; r < 4; ++r)
            out[((size_t)(b * N_ + orow0 + r)) * F_ + ch] = oacc[d][r] * l_[r] * wov + bov;
    }
}

extern "C" void kernel_launch(void* const* d_in, const int* in_sizes, int n_in,
                              void* d_out, int out_size, void* d_ws, size_t ws_size,
                              hipStream_t stream) {
    const float* x  = (const float*)d_in[0];
    const float* wq = (const float*)d_in[1];
    const float* bq = (const float*)d_in[2];
    const float* wk = (const float*)d_in[3];
    const float* bk = (const float*)d_in[4];
    const float* wv = (const float*)d_in[5];
    const float* bv = (const float*)d_in[6];
    const float* wo = (const float*)d_in[7];
    const float* bo = (const float*)d_in[8];
    float* out = (float*)d_out;

    const size_t elems = (size_t)B_ * H_ * N_ * D_;      // 12,582,912
    const size_t need  = elems * 2 * 2;                  // K + V, bf16
    if (ws_size >= need) {
        short* Ktw = (short*)d_ws;
        short* Vtw = Ktw + elems;
        prep_kv<<<dim3(B_ * H_ * NT), dim3(256), 0, stream>>>(x, wk, bk, wv, bv, Ktw, Vtw);
        attn_main<<<dim3(B_ * H_ * (N_ / QB)), dim3(512), 0, stream>>>(
            x, wq, bq, Ktw, Vtw, wo, bo, out);
    } else {
        attn_fused<<<dim3(B_ * H_ * (N_ / 64)), dim3(256), 0, stream>>>(
            x, wq, bq, wk, bk, wv, bv, wo, bo, out);
    }
}

// Round 6
// 101.139 us; speedup vs baseline: 2.6088x; 1.1301x over previous
//
#include <hip/hip_runtime.h>
#include <hip/hip_bf16.h>
#include <cstdint>
#include <cstddef>

typedef __attribute__((ext_vector_type(8))) short short8;
typedef __attribute__((ext_vector_type(4))) short short4v;
typedef __attribute__((ext_vector_type(4))) float f32x4;
typedef __attribute__((ext_vector_type(16))) float f32x16;
typedef __attribute__((ext_vector_type(4))) unsigned int uint4v;

static constexpr int B_ = 16, N_ = 1024, F_ = 768, H_ = 12, D_ = 64;
static constexpr int NB = 64, NT = N_ / NB;      // kv tile rows, #tiles
static constexpr int QB = 128;                   // q rows per block (main)
static constexpr float RSCALE = 0.036084391824351615f;               // 1/sqrt(768)
static constexpr float QSCALE = 0.036084391824351615f * 1.4426950408889634f; // * log2(e)
static constexpr float DEFER_THR = 8.0f;         // exp2-domain defer-max threshold

__device__ __forceinline__ short f2bf(float f) {
    return __builtin_bit_cast(short, __float2bfloat16(f));
}
__device__ __forceinline__ unsigned cvtpk(float lo, float hi) {
    unsigned r;
    asm("v_cvt_pk_bf16_f32 %0, %1, %2" : "=v"(r) : "v"(lo), "v"(hi));
    return r;
}

#define GLB(p)  ((const __attribute__((address_space(1))) void*)(p))
#define LDSP(p) ((__attribute__((address_space(3))) void*)(p))

// ---------------------------------------------------------------------------
// Prep: K row-major [bh][t][n][ch], V transposed [bh][t][d][n], bf16,
// 8KB tiles, 16B chunks XOR-swizzled by (row&7).
// ---------------------------------------------------------------------------
__global__ void __launch_bounds__(256) prep_kv(
    const float* __restrict__ x,
    const float* __restrict__ wk, const float* __restrict__ bk,
    const float* __restrict__ wv, const float* __restrict__ bv,
    short* __restrict__ Kt, short* __restrict__ Vt)
{
    const int bid = blockIdx.x;          // = bh*16 + t
    const int t   = bid & 15;
    const int bh  = bid >> 4;
    const int h   = bh % H_, b = bh / H_;
    const int nb  = t * NB;
    const int tid = threadIdx.x;
    short* Ktile = Kt + ((size_t)bid << 12);
    short* Vtile = Vt + ((size_t)bid << 12);

    { // K: thread -> (row n, 16 channels)
        const int n = tid >> 2, sg = tid & 3;
        const float* xr  = x  + ((size_t)(b * N_ + nb + n)) * F_ + h * D_ + sg * 16;
        const float* wkp = wk + h * D_ + sg * 16;
        const float* bkp = bk + h * D_ + sg * 16;
        float xv[16];
        #pragma unroll
        for (int q = 0; q < 4; ++q) *(float4*)&xv[q * 4] = *(const float4*)(xr + q * 4);
        short kb[16];
        #pragma unroll
        for (int i = 0; i < 16; ++i) kb[i] = f2bf(xv[i] * wkp[i] + bkp[i]);
        const int swz = n & 7;
        #pragma unroll
        for (int c2 = 0; c2 < 2; ++c2) {
            const int c = sg * 2 + c2;
            *(short8*)&Ktile[n * 64 + ((c ^ swz) << 3)] = *(short8*)&kb[c2 * 8];
        }
    }
    { // V^T: thread -> (channel d, 16 n values)
        const int d = tid & 63, ng = tid >> 6;
        const float wvd = wv[h * D_ + d], bvd = bv[h * D_ + d];
        const float* xc = x + ((size_t)(b * N_ + nb + ng * 16)) * F_ + h * D_ + d;
        short vb[16];
        #pragma unroll
        for (int j = 0; j < 16; ++j) vb[j] = f2bf(xc[(size_t)j * F_] * wvd + bvd);
        const int swz = d & 7;
        #pragma unroll
        for (int c2 = 0; c2 < 2; ++c2) {
            const int c = ng * 2 + c2;
            *(short8*)&Vtile[d * 64 + ((c ^ swz) << 3)] = *(short8*)&vb[c2 * 8];
        }
    }
}

// ---------------------------------------------------------------------------
// Main: 4 waves x 32 q-rows (QB=128), 32x32x16 MFMA, swapped QK^T (S^T),
// O^T accum. m_ folded into MFMA C-input (S arrives pre-subtracted).
// Tree reductions for row max/sum. P^T packed in plain register order;
// V^T A-fragment loaded with the same placement function (verified R5).
// ---------------------------------------------------------------------------
__global__ void __launch_bounds__(256, 4) attn_main(
    const float* __restrict__ x,
    const float* __restrict__ wq, const float* __restrict__ bq,
    const short* __restrict__ Kt, const short* __restrict__ Vt,
    const float* __restrict__ wo, const float* __restrict__ bo,
    float* __restrict__ out)
{
    __shared__ short KV[2][2][4096];     // [dbuf][K/V][64 rows x 64 ch swizzled]

    const int tid  = threadIdx.x;
    const int w    = tid >> 6, lane = tid & 63;
    const int q32  = lane & 31, hi = lane >> 5;

    const int orig = blockIdx.x;
    const int sb   = (orig & 7) * 192 + (orig >> 3);  // XCD swizzle (1536%8==0)
    const int qt   = sb & 7, bh = sb >> 3;
    const int h    = bh % H_, b = bh / H_;
    const int qrow0 = qt * QB + w * 32;
    const int qa    = qrow0 + q32;                   // this lane's q row

    // ---- Q as B-fragments ----
    short8 qf[4];
    {
        const float* xq = x + ((size_t)(b * N_ + qa)) * F_ + h * D_;
        #pragma unroll
        for (int s = 0; s < 4; ++s) {
            const int ch0 = s * 16 + hi * 8;
            float4 a0 = *(const float4*)(xq + ch0);
            float4 a1 = *(const float4*)(xq + ch0 + 4);
            const float* wqp = wq + h * D_ + ch0;
            const float* bqp = bq + h * D_ + ch0;
            float q8[8] = {a0.x,a0.y,a0.z,a0.w,a1.x,a1.y,a1.z,a1.w};
            uint4v u;
            #pragma unroll
            for (int j = 0; j < 4; ++j) {
                const float lo = (q8[2*j]   * wqp[2*j]   + bqp[2*j])   * QSCALE;
                const float hf = (q8[2*j+1] * wqp[2*j+1] + bqp[2*j+1]) * QSCALE;
                u[j] = cvtpk(lo, hf);
            }
            qf[s] = __builtin_bit_cast(short8, u);
        }
    }

    // LDS fragment chunk offsets (elems); row-swizzle = q32&7 (rows differ by 32)
    const int swz = q32 & 7;
    int coff[4];
    #pragma unroll
    for (int s = 0; s < 4; ++s) coff[s] = (((s * 2 + hi) ^ swz) << 3);
    const int rA = q32 * 64;           // row base, subtile 0
    const int rB = (32 + q32) * 64;    // row base, subtile 1

    float m_ = 0.f, l_ = 0.f;          // m_=0 init is safe: rebase is exact
    f32x16 oA, oB;
    #pragma unroll
    for (int r = 0; r < 16; ++r) { oA[r] = 0.f; oB[r] = 0.f; }

    const size_t base = ((size_t)bh) * (NT * 4096);
    auto stage = [&](int buf, int tt) {
        const short* tk = Kt + base + ((size_t)tt << 12) + w * 1024 + (lane << 3);
        const short* tv = Vt + base + ((size_t)tt << 12) + w * 1024 + (lane << 3);
        __builtin_amdgcn_global_load_lds(GLB(tk),       LDSP(&KV[buf][0][w*1024]),       16, 0, 0);
        __builtin_amdgcn_global_load_lds(GLB(tk + 512), LDSP(&KV[buf][0][w*1024 + 512]), 16, 0, 0);
        __builtin_amdgcn_global_load_lds(GLB(tv),       LDSP(&KV[buf][1][w*1024]),       16, 0, 0);
        __builtin_amdgcn_global_load_lds(GLB(tv + 512), LDSP(&KV[buf][1][w*1024 + 512]), 16, 0, 0);
    };

    stage(0, 0);

    for (int t = 0; t < NT; ++t) {
        const int cur = t & 1;
        __syncthreads();                      // drains tile-t loads (issued 1 tile ago)
        if (t + 1 < NT) stage(cur ^ 1, t + 1);   // overlaps with this tile's compute
        const short* Kb = &KV[cur][0][0];
        const short* Vb = &KV[cur][1][0];

        // ---- S^T - m = K Q^T + C(-m) : lane holds 32 pre-shifted scores ----
        const float negm = -m_;
        f32x16 sA, sB;
        #pragma unroll
        for (int r = 0; r < 16; ++r) { sA[r] = negm; sB[r] = negm; }
        __builtin_amdgcn_s_setprio(1);
        #pragma unroll
        for (int s = 0; s < 4; ++s) {
            short8 k0 = *(const short8*)&Kb[rA + coff[s]];
            short8 k1 = *(const short8*)&Kb[rB + coff[s]];
            sA = __builtin_amdgcn_mfma_f32_32x32x16_bf16(k0, qf[s], sA, 0, 0, 0);
            sB = __builtin_amdgcn_mfma_f32_32x32x16_bf16(k1, qf[s], sB, 0, 0, 0);
        }
        __builtin_amdgcn_s_setprio(0);

        // ---- row max: tree (depth 5) + one cross-half shfl ----
        float mx[16];
        #pragma unroll
        for (int r = 0; r < 16; ++r) mx[r] = fmaxf(sA[r], sB[r]);
        #pragma unroll
        for (int off = 8; off > 0; off >>= 1) {
            #pragma unroll
            for (int i = 0; i < 8; ++i)
                if (i < off) mx[i] = fmaxf(mx[i], mx[i + off]);
        }
        const float tm = fmaxf(mx[0], __shfl_xor(mx[0], 32, 64));

        // ---- defer-max: rebase only when headroom exceeded (exact) ----
        if (!__all(tm <= DEFER_THR)) {
            const float corr = __builtin_amdgcn_exp2f(-tm);
            l_ *= corr;
            #pragma unroll
            for (int r = 0; r < 16; ++r) { oA[r] *= corr; oB[r] *= corr; }
            #pragma unroll
            for (int r = 0; r < 16; ++r) { sA[r] -= tm; sB[r] -= tm; }
            m_ += tm;
        }

        // ---- P = exp2(shifted S); row sum via tree ----
        float e[32];
        #pragma unroll
        for (int r = 0; r < 16; ++r) {
            e[r]      = __builtin_amdgcn_exp2f(sA[r]);
            e[16 + r] = __builtin_amdgcn_exp2f(sB[r]);
        }
        float su[16];
        #pragma unroll
        for (int i = 0; i < 16; ++i) su[i] = e[i] + e[i + 16];
        #pragma unroll
        for (int off = 8; off > 0; off >>= 1) {
            #pragma unroll
            for (int i = 0; i < 8; ++i)
                if (i < off) su[i] += su[i + off];
        }
        l_ += su[0] + __shfl_xor(su[0], 32, 64);

        // ---- pack P^T B-frags: plain register order, 16 cvt_pk ----
        short8 pf[4];
        {
            uint4v u0, u1, u2, u3;
            u0[0] = cvtpk(e[0],  e[1]);  u0[1] = cvtpk(e[2],  e[3]);
            u0[2] = cvtpk(e[4],  e[5]);  u0[3] = cvtpk(e[6],  e[7]);
            u1[0] = cvtpk(e[8],  e[9]);  u1[1] = cvtpk(e[10], e[11]);
            u1[2] = cvtpk(e[12], e[13]); u1[3] = cvtpk(e[14], e[15]);
            u2[0] = cvtpk(e[16], e[17]); u2[1] = cvtpk(e[18], e[19]);
            u2[2] = cvtpk(e[20], e[21]); u2[3] = cvtpk(e[22], e[23]);
            u3[0] = cvtpk(e[24], e[25]); u3[1] = cvtpk(e[26], e[27]);
            u3[2] = cvtpk(e[28], e[29]); u3[3] = cvtpk(e[30], e[31]);
            pf[0] = __builtin_bit_cast(short8, u0);
            pf[1] = __builtin_bit_cast(short8, u1);
            pf[2] = __builtin_bit_cast(short8, u2);
            pf[3] = __builtin_bit_cast(short8, u3);
        }

        // ---- O^T += V^T P^T ; V loaded with P's placement function ----
        __builtin_amdgcn_s_setprio(1);
        #pragma unroll
        for (int s = 0; s < 4; ++s) {
            const int cLo = ((2*s    ) ^ swz) << 3;
            const int cHi = ((2*s + 1) ^ swz) << 3;
            short4v aLo = *(const short4v*)&Vb[rA + cLo + 4*hi];
            short4v aHi = *(const short4v*)&Vb[rA + cHi + 4*hi];
            short4v bLo = *(const short4v*)&Vb[rB + cLo + 4*hi];
            short4v bHi = *(const short4v*)&Vb[rB + cHi + 4*hi];
            short8 v0 = {aLo[0],aLo[1],aLo[2],aLo[3], aHi[0],aHi[1],aHi[2],aHi[3]};
            short8 v1 = {bLo[0],bLo[1],bLo[2],bLo[3], bHi[0],bHi[1],bHi[2],bHi[3]};
            oA = __builtin_amdgcn_mfma_f32_32x32x16_bf16(v0, pf[s], oA, 0, 0, 0);
            oB = __builtin_amdgcn_mfma_f32_32x32x16_bf16(v1, pf[s], oB, 0, 0, 0);
        }
        __builtin_amdgcn_s_setprio(0);
    }

    // ---- epilogue: O^T[d][q=q32]; reg 4j+i -> d = dsb*32 + 8j + 4hi + i ----
    const float invl = 1.f / l_;
    float* orow = out + ((size_t)(b * N_ + qa)) * F_;
    #pragma unroll
    for (int dsb = 0; dsb < 2; ++dsb) {
        #pragma unroll
        for (int j = 0; j < 4; ++j) {
            const int ch = h * D_ + dsb * 32 + 8 * j + 4 * hi;
            float4 wv = *(const float4*)(wo + ch);
            float4 bv = *(const float4*)(bo + ch);
            float4 o4;
            if (dsb == 0) {
                o4.x = oA[4*j+0] * invl * wv.x + bv.x;
                o4.y = oA[4*j+1] * invl * wv.y + bv.y;
                o4.z = oA[4*j+2] * invl * wv.z + bv.z;
                o4.w = oA[4*j+3] * invl * wv.w + bv.w;
            } else {
                o4.x = oB[4*j+0] * invl * wv.x + bv.x;
                o4.y = oB[4*j+1] * invl * wv.y + bv.y;
                o4.z = oB[4*j+2] * invl * wv.z + bv.z;
                o4.w = oB[4*j+3] * invl * wv.w + bv.w;
            }
            *(float4*)(orow + ch) = o4;
        }
    }
}

// ---------------------------------------------------------------------------
// Fallback (round-1 kernel) if workspace is too small
// ---------------------------------------------------------------------------
__global__ void __launch_bounds__(256) attn_fused(
    const float* __restrict__ x,
    const float* __restrict__ wq, const float* __restrict__ bq,
    const float* __restrict__ wk, const float* __restrict__ bk,
    const float* __restrict__ wv, const float* __restrict__ bv,
    const float* __restrict__ wo, const float* __restrict__ bo,
    float* __restrict__ out)
{
    __shared__ short Klds[64][72];
    __shared__ short Vt[64][72];
    __shared__ short Plds[4][16][72];

    const int tid = threadIdx.x;
    const int wave = tid >> 6, lane = tid & 63;
    const int g = lane >> 4, cc = lane & 15;
    const int bid = blockIdx.x;
    const int qt = bid & 15, t1 = bid >> 4;
    const int h = t1 % H_, b = t1 / H_;

    const int qrow = qt * 64 + wave * 16 + cc;
    const float* xq = x + ((size_t)(b * N_ + qrow)) * F_ + h * D_;
    short8 qf[2];
    #pragma unroll
    for (int kc = 0; kc < 2; ++kc) {
        const int dd = kc * 32 + g * 8;
        float4 a0 = *(const float4*)(xq + dd);
        float4 a1 = *(const float4*)(xq + dd + 4);
        float qa[8] = {a0.x,a0.y,a0.z,a0.w,a1.x,a1.y,a1.z,a1.w};
        #pragma unroll
        for (int i = 0; i < 8; ++i) {
            const int ch = h * D_ + dd + i;
            qf[kc][i] = f2bf((qa[i] * wq[ch] + bq[ch]) * RSCALE);
        }
    }
    const int srow = tid >> 2, seg = tid & 3;
    const int cb = h * D_ + seg * 16;
    float m_[4], l_[4];
    f32x4 oacc[4];
    #pragma unroll
    for (int r = 0; r < 4; ++r) { m_[r] = -INFINITY; l_[r] = 0.f; oacc[r] = (f32x4){0,0,0,0}; }

    for (int nb = 0; nb < N_; nb += 64) {
        __syncthreads();
        {
            const float* xr = x + ((size_t)(b * N_ + nb + srow)) * F_ + cb;
            float4 x0 = *(const float4*)(xr + 0), x1 = *(const float4*)(xr + 4);
            float4 x2 = *(const float4*)(xr + 8), x3 = *(const float4*)(xr + 12);
            float xf[16] = {x0.x,x0.y,x0.z,x0.w,x1.x,x1.y,x1.z,x1.w,
                            x2.x,x2.y,x2.z,x2.w,x3.x,x3.y,x3.z,x3.w};
            short8 k0, k1;
            #pragma unroll
            for (int i = 0; i < 8; ++i) {
                k0[i] = f2bf(xf[i] * wk[cb+i] + bk[cb+i]);
                k1[i] = f2bf(xf[i+8] * wk[cb+i+8] + bk[cb+i+8]);
            }
            *(short8*)&Klds[srow][seg*16] = k0;
            *(short8*)&Klds[srow][seg*16+8] = k1;
            #pragma unroll
            for (int i = 0; i < 16; ++i)
                Vt[seg*16+i][srow] = f2bf(xf[i] * wv[cb+i] + bv[cb+i]);
        }
        __syncthreads();
        f32x4 s[4];
        #pragma unroll
        for (int sub = 0; sub < 4; ++sub) {
            f32x4 acc = (f32x4){0,0,0,0};
            #pragma unroll
            for (int kc = 0; kc < 2; ++kc) {
                short8 kf = *(short8*)&Klds[sub*16+cc][kc*32+g*8];
                acc = __builtin_amdgcn_mfma_f32_16x16x32_bf16(qf[kc], kf, acc, 0,0,0);
            }
            s[sub] = acc;
        }
        float tm[4];
        #pragma unroll
        for (int r = 0; r < 4; ++r)
            tm[r] = fmaxf(fmaxf(s[0][r], s[1][r]), fmaxf(s[2][r], s[3][r]));
        #pragma unroll
        for (int r = 0; r < 4; ++r)
            #pragma unroll
            for (int off = 1; off < 16; off <<= 1)
                tm[r] = fmaxf(tm[r], __shfl_xor(tm[r], off, 64));
        float corr[4], ps[4];
        #pragma unroll
        for (int r = 0; r < 4; ++r) {
            float mn = fmaxf(m_[r], tm[r]);
            corr[r] = __expf(m_[r] - mn);
            m_[r] = mn; ps[r] = 0.f;
        }
        #pragma unroll
        for (int sub = 0; sub < 4; ++sub)
            #pragma unroll
            for (int r = 0; r < 4; ++r) {
                float p = __expf(s[sub][r] - m_[r]);
                s[sub][r] = p; ps[r] += p;
            }
        #pragma unroll
        for (int r = 0; r < 4; ++r) {
            #pragma unroll
            for (int off = 1; off < 16; off <<= 1)
                ps[r] += __shfl_xor(ps[r], off, 64);
            l_[r] = l_[r] * corr[r] + ps[r];
        }
        #pragma unroll
        for (int d = 0; d < 4; ++d)
            #pragma unroll
            for (int r = 0; r < 4; ++r) oacc[d][r] *= corr[r];
        #pragma unroll
        for (int sub = 0; sub < 4; ++sub)
            #pragma unroll
            for (int r = 0; r < 4; ++r)
                Plds[wave][g*4+r][sub*16+cc] = f2bf(s[sub][r]);
        short8 pf[2];
        #pragma unroll
        for (int nc = 0; nc < 2; ++nc)
            pf[nc] = *(short8*)&Plds[wave][cc][nc*32+g*8];
        #pragma unroll
        for (int d = 0; d < 4; ++d)
            #pragma unroll
            for (int nc = 0; nc < 2; ++nc) {
                short8 vf = *(short8*)&Vt[d*16+cc][nc*32+g*8];
                oacc[d] = __builtin_amdgcn_mfma_f32_16x16x32_bf16(pf[nc], vf, oacc[d], 0,0,0);
            }
    }
    #pragma unroll
    for (int r = 0; r < 4; ++r) l_[r] = 1.f / l_[r];
    const int orow0 = qt * 64 + wave * 16 + g * 4;
    #pragma unroll
    for (int d = 0; d < 4; ++d) {
        const int ch = h * D_ + d * 16 + cc;
        const float wov = wo[ch], bov = bo[ch];
        #pragma unroll
        for (int r = 0; r < 4; ++r)
            out[((size_t)(b * N_ + orow0 + r)) * F_ + ch] = oacc[d][r] * l_[r] * wov + bov;
    }
}

extern "C" void kernel_launch(void* const* d_in, const int* in_sizes, int n_in,
                              void* d_out, int out_size, void* d_ws, size_t ws_size,
                              hipStream_t stream) {
    const float* x  = (const float*)d_in[0];
    const float* wq = (const float*)d_in[1];
    const float* bq = (const float*)d_in[2];
    const float* wk = (const float*)d_in[3];
    const float* bk = (const float*)d_in[4];
    const float* wv = (const float*)d_in[5];
    const float* bv = (const float*)d_in[6];
    const float* wo = (const float*)d_in[7];
    const float* bo = (const float*)d_in[8];
    float* out = (float*)d_out;

    const size_t elems = (size_t)B_ * H_ * N_ * D_;      // 12,582,912
    const size_t need  = elems * 2 * 2;                  // K + V, bf16
    if (ws_size >= need) {
        short* Ktw = (short*)d_ws;
        short* Vtw = Ktw + elems;
        prep_kv<<<dim3(B_ * H_ * NT), dim3(256), 0, stream>>>(x, wk, bk, wv, bv, Ktw, Vtw);
        attn_main<<<dim3(B_ * H_ * (N_ / QB)), dim3(256), 0, stream>>>(
            x, wq, bq, Ktw, Vtw, wo, bo, out);
    } else {
        attn_fused<<<dim3(B_ * H_ * (N_ / 64)), dim3(256), 0, stream>>>(
            x, wq, bq, wk, bk, wv, bv, wo, bo, out);
    }
}

// Round 7
// 96.132 us; speedup vs baseline: 2.7447x; 1.0521x over previous
//
#include <hip/hip_runtime.h>
#include <hip/hip_bf16.h>
#include <cstdint>
#include <cstddef>

typedef __attribute__((ext_vector_type(8))) short short8;
typedef __attribute__((ext_vector_type(4))) float f32x4;
typedef __attribute__((ext_vector_type(16))) float f32x16;
typedef __attribute__((ext_vector_type(4))) unsigned int uint4v;

static constexpr int B_ = 16, N_ = 1024, F_ = 768, H_ = 12, D_ = 64;
static constexpr int NB = 64, NT = N_ / NB;      // kv tile rows, #tiles
static constexpr int QB = 128;                   // q rows per block (main)
static constexpr float RSCALE = 0.036084391824351615f;               // 1/sqrt(768)
static constexpr float QSCALE = 0.036084391824351615f * 1.4426950408889634f; // * log2(e)
static constexpr float DEFER_THR = 8.0f;         // exp2-domain defer-max threshold

__device__ __forceinline__ short f2bf(float f) {
    return __builtin_bit_cast(short, __float2bfloat16(f));
}
__device__ __forceinline__ unsigned cvtpk(float lo, float hi) {
    unsigned r;
    asm("v_cvt_pk_bf16_f32 %0, %1, %2" : "=v"(r) : "v"(lo), "v"(hi));
    return r;
}

#define GLB(p)  ((const __attribute__((address_space(1))) void*)(p))
#define LDSP(p) ((__attribute__((address_space(3))) void*)(p))

// ---------------------------------------------------------------------------
// Prep: K row-major [bh][t][n][ch], V transposed+slab-permuted [bh][t][d][kv'],
// bf16, 8KB tiles, 16B chunks XOR-swizzled by (row&7).
// V chunk (2s+hi) holds kv = {16s+4hi+0..3, 16s+8+4hi+0..3}  (matches the
// P^T register placement, so main's V read is one b128 at coff[s]).
// ---------------------------------------------------------------------------
__global__ void __launch_bounds__(256) prep_kv(
    const float* __restrict__ x,
    const float* __restrict__ wk, const float* __restrict__ bk,
    const float* __restrict__ wv, const float* __restrict__ bv,
    short* __restrict__ Kt, short* __restrict__ Vt)
{
    const int bid = blockIdx.x;          // = bh*16 + t
    const int t   = bid & 15;
    const int bh  = bid >> 4;
    const int h   = bh % H_, b = bh / H_;
    const int nb  = t * NB;
    const int tid = threadIdx.x;
    short* Ktile = Kt + ((size_t)bid << 12);
    short* Vtile = Vt + ((size_t)bid << 12);

    { // K: thread -> (row n, 16 channels)
        const int n = tid >> 2, sg = tid & 3;
        const float* xr  = x  + ((size_t)(b * N_ + nb + n)) * F_ + h * D_ + sg * 16;
        const float* wkp = wk + h * D_ + sg * 16;
        const float* bkp = bk + h * D_ + sg * 16;
        float xv[16];
        #pragma unroll
        for (int q = 0; q < 4; ++q) *(float4*)&xv[q * 4] = *(const float4*)(xr + q * 4);
        short kb[16];
        #pragma unroll
        for (int i = 0; i < 16; ++i) kb[i] = f2bf(xv[i] * wkp[i] + bkp[i]);
        const int swz = n & 7;
        #pragma unroll
        for (int c2 = 0; c2 < 2; ++c2) {
            const int c = sg * 2 + c2;
            *(short8*)&Ktile[n * 64 + ((c ^ swz) << 3)] = *(short8*)&kb[c2 * 8];
        }
    }
    { // V^T: thread -> (channel d, one 16-kv slab s = ng); slab-permuted pack
        const int d = tid & 63, ng = tid >> 6;
        const float wvd = wv[h * D_ + d], bvd = bv[h * D_ + d];
        const float* xc = x + ((size_t)(b * N_ + nb + ng * 16)) * F_ + h * D_ + d;
        short vb[16];
        #pragma unroll
        for (int j = 0; j < 16; ++j) vb[j] = f2bf(xc[(size_t)j * F_] * wvd + bvd);
        const int swz = d & 7;
        short8 c0 = {vb[0], vb[1], vb[2],  vb[3],  vb[8],  vb[9],  vb[10], vb[11]};
        short8 c1 = {vb[4], vb[5], vb[6],  vb[7],  vb[12], vb[13], vb[14], vb[15]};
        *(short8*)&Vtile[d * 64 + (((ng * 2    ) ^ swz) << 3)] = c0;
        *(short8*)&Vtile[d * 64 + (((ng * 2 + 1) ^ swz) << 3)] = c1;
    }
}

// ---------------------------------------------------------------------------
// Main: 4 waves x 32 q-rows (QB=128), 32x32x16 MFMA, swapped QK^T (S^T),
// O^T accum. Split-subtile schedule: softmax(kv 0..31) overlaps S-MFMAs of
// kv 32..63; softmax(32..63) overlaps PV of 0..31. Per-half online rebase.
// V read is one swizzled b128 at coff[s] (conflict-free, same form as K).
// ---------------------------------------------------------------------------
__global__ void __launch_bounds__(256, 4) attn_main(
    const float* __restrict__ x,
    const float* __restrict__ wq, const float* __restrict__ bq,
    const short* __restrict__ Kt, const short* __restrict__ Vt,
    const float* __restrict__ wo, const float* __restrict__ bo,
    float* __restrict__ out)
{
    __shared__ short KV[2][2][4096];     // [dbuf][K/V][64 rows x 64 ch swizzled]

    const int tid  = threadIdx.x;
    const int w    = tid >> 6, lane = tid & 63;
    const int q32  = lane & 31, hi = lane >> 5;

    const int orig = blockIdx.x;
    const int sb   = (orig & 7) * 192 + (orig >> 3);  // XCD swizzle (1536%8==0)
    const int qt   = sb & 7, bh = sb >> 3;
    const int h    = bh % H_, b = bh / H_;
    const int qrow0 = qt * QB + w * 32;
    const int qa    = qrow0 + q32;                   // this lane's q row

    // ---- Q as B-fragments ----
    short8 qf[4];
    {
        const float* xq = x + ((size_t)(b * N_ + qa)) * F_ + h * D_;
        #pragma unroll
        for (int s = 0; s < 4; ++s) {
            const int ch0 = s * 16 + hi * 8;
            float4 a0 = *(const float4*)(xq + ch0);
            float4 a1 = *(const float4*)(xq + ch0 + 4);
            const float* wqp = wq + h * D_ + ch0;
            const float* bqp = bq + h * D_ + ch0;
            float q8[8] = {a0.x,a0.y,a0.z,a0.w,a1.x,a1.y,a1.z,a1.w};
            uint4v u;
            #pragma unroll
            for (int j = 0; j < 4; ++j) {
                const float lo = (q8[2*j]   * wqp[2*j]   + bqp[2*j])   * QSCALE;
                const float hf = (q8[2*j+1] * wqp[2*j+1] + bqp[2*j+1]) * QSCALE;
                u[j] = cvtpk(lo, hf);
            }
            qf[s] = __builtin_bit_cast(short8, u);
        }
    }

    // LDS fragment chunk offsets (elems); row-swizzle = q32&7 (rows differ by 32)
    const int swz = q32 & 7;
    int coff[4];
    #pragma unroll
    for (int s = 0; s < 4; ++s) coff[s] = (((s * 2 + hi) ^ swz) << 3);
    const int rA = q32 * 64;           // row base, subtile 0
    const int rB = (32 + q32) * 64;    // row base, subtile 1

    float m_ = 0.f, l_ = 0.f;          // m_=0 init is safe: rebase is exact
    f32x16 oA, oB;
    #pragma unroll
    for (int r = 0; r < 16; ++r) { oA[r] = 0.f; oB[r] = 0.f; }

    const size_t base = ((size_t)bh) * (NT * 4096);
    auto stage = [&](int buf, int tt) {
        const short* tk = Kt + base + ((size_t)tt << 12) + w * 1024 + (lane << 3);
        const short* tv = Vt + base + ((size_t)tt << 12) + w * 1024 + (lane << 3);
        __builtin_amdgcn_global_load_lds(GLB(tk),       LDSP(&KV[buf][0][w*1024]),       16, 0, 0);
        __builtin_amdgcn_global_load_lds(GLB(tk + 512), LDSP(&KV[buf][0][w*1024 + 512]), 16, 0, 0);
        __builtin_amdgcn_global_load_lds(GLB(tv),       LDSP(&KV[buf][1][w*1024]),       16, 0, 0);
        __builtin_amdgcn_global_load_lds(GLB(tv + 512), LDSP(&KV[buf][1][w*1024 + 512]), 16, 0, 0);
    };

    stage(0, 0);

    for (int t = 0; t < NT; ++t) {
        const int cur = t & 1;
        __syncthreads();                      // drains tile-t loads (issued 1 tile ago)
        if (t + 1 < NT) stage(cur ^ 1, t + 1);   // overlaps with this tile's compute
        const short* Kb = &KV[cur][0][0];
        const short* Vb = &KV[cur][1][0];

        // ---- S^T - m = K Q^T + C(-m) ----
        const float negm = -m_;
        f32x16 sA, sB;
        #pragma unroll
        for (int r = 0; r < 16; ++r) { sA[r] = negm; sB[r] = negm; }
        #pragma unroll
        for (int s = 0; s < 4; ++s) {
            short8 k0 = *(const short8*)&Kb[rA + coff[s]];
            short8 k1 = *(const short8*)&Kb[rB + coff[s]];
            sA = __builtin_amdgcn_mfma_f32_32x32x16_bf16(k0, qf[s], sA, 0, 0, 0);
            sB = __builtin_amdgcn_mfma_f32_32x32x16_bf16(k1, qf[s], sB, 0, 0, 0);
        }

        // ================= subtile A (kv 0..31) =================
        {
            float mx[8];
            #pragma unroll
            for (int i = 0; i < 8; ++i) mx[i] = fmaxf(sA[i], sA[i + 8]);
            #pragma unroll
            for (int off = 4; off > 0; off >>= 1)
                #pragma unroll
                for (int i = 0; i < 4; ++i)
                    if (i < off) mx[i] = fmaxf(mx[i], mx[i + off]);
            const float tmA = fmaxf(mx[0], __shfl_xor(mx[0], 32, 64));
            if (!__all(tmA <= DEFER_THR)) {
                const float corr = __builtin_amdgcn_exp2f(-tmA);
                l_ *= corr;
                #pragma unroll
                for (int r = 0; r < 16; ++r) { oA[r] *= corr; oB[r] *= corr; }
                #pragma unroll
                for (int r = 0; r < 16; ++r) { sA[r] -= tmA; sB[r] -= tmA; }
                m_ += tmA;
            }
            #pragma unroll
            for (int r = 0; r < 16; ++r) sA[r] = __builtin_amdgcn_exp2f(sA[r]);
            float su[8];
            #pragma unroll
            for (int i = 0; i < 8; ++i) su[i] = sA[i] + sA[i + 8];
            #pragma unroll
            for (int off = 4; off > 0; off >>= 1)
                #pragma unroll
                for (int i = 0; i < 4; ++i)
                    if (i < off) su[i] += su[i + off];
            l_ += su[0] + __shfl_xor(su[0], 32, 64);
        }
        short8 pfA[2];
        {
            uint4v u0, u1;
            u0[0] = cvtpk(sA[0],  sA[1]);  u0[1] = cvtpk(sA[2],  sA[3]);
            u0[2] = cvtpk(sA[4],  sA[5]);  u0[3] = cvtpk(sA[6],  sA[7]);
            u1[0] = cvtpk(sA[8],  sA[9]);  u1[1] = cvtpk(sA[10], sA[11]);
            u1[2] = cvtpk(sA[12], sA[13]); u1[3] = cvtpk(sA[14], sA[15]);
            pfA[0] = __builtin_bit_cast(short8, u0);
            pfA[1] = __builtin_bit_cast(short8, u1);
        }
        // ---- PV for kv 0..31 (slabs s=0,1); overlaps softmax of subtile B ----
        #pragma unroll
        for (int s = 0; s < 2; ++s) {
            short8 v0 = *(const short8*)&Vb[rA + coff[s]];
            short8 v1 = *(const short8*)&Vb[rB + coff[s]];
            oA = __builtin_amdgcn_mfma_f32_32x32x16_bf16(v0, pfA[s], oA, 0, 0, 0);
            oB = __builtin_amdgcn_mfma_f32_32x32x16_bf16(v1, pfA[s], oB, 0, 0, 0);
        }

        // ================= subtile B (kv 32..63) =================
        {
            float mx[8];
            #pragma unroll
            for (int i = 0; i < 8; ++i) mx[i] = fmaxf(sB[i], sB[i + 8]);
            #pragma unroll
            for (int off = 4; off > 0; off >>= 1)
                #pragma unroll
                for (int i = 0; i < 4; ++i)
                    if (i < off) mx[i] = fmaxf(mx[i], mx[i + off]);
            const float tmB = fmaxf(mx[0], __shfl_xor(mx[0], 32, 64));
            if (!__all(tmB <= DEFER_THR)) {
                const float corr = __builtin_amdgcn_exp2f(-tmB);
                l_ *= corr;
                #pragma unroll
                for (int r = 0; r < 16; ++r) { oA[r] *= corr; oB[r] *= corr; }
                #pragma unroll
                for (int r = 0; r < 16; ++r) sB[r] -= tmB;
                m_ += tmB;
            }
            #pragma unroll
            for (int r = 0; r < 16; ++r) sB[r] = __builtin_amdgcn_exp2f(sB[r]);
            float su[8];
            #pragma unroll
            for (int i = 0; i < 8; ++i) su[i] = sB[i] + sB[i + 8];
            #pragma unroll
            for (int off = 4; off > 0; off >>= 1)
                #pragma unroll
                for (int i = 0; i < 4; ++i)
                    if (i < off) su[i] += su[i + off];
            l_ += su[0] + __shfl_xor(su[0], 32, 64);
        }
        short8 pfB[2];
        {
            uint4v u2, u3;
            u2[0] = cvtpk(sB[0],  sB[1]);  u2[1] = cvtpk(sB[2],  sB[3]);
            u2[2] = cvtpk(sB[4],  sB[5]);  u2[3] = cvtpk(sB[6],  sB[7]);
            u3[0] = cvtpk(sB[8],  sB[9]);  u3[1] = cvtpk(sB[10], sB[11]);
            u3[2] = cvtpk(sB[12], sB[13]); u3[3] = cvtpk(sB[14], sB[15]);
            pfB[0] = __builtin_bit_cast(short8, u2);
            pfB[1] = __builtin_bit_cast(short8, u3);
        }
        // ---- PV for kv 32..63 (slabs s=2,3) ----
        #pragma unroll
        for (int s = 2; s < 4; ++s) {
            short8 v0 = *(const short8*)&Vb[rA + coff[s]];
            short8 v1 = *(const short8*)&Vb[rB + coff[s]];
            oA = __builtin_amdgcn_mfma_f32_32x32x16_bf16(v0, pfB[s - 2], oA, 0, 0, 0);
            oB = __builtin_amdgcn_mfma_f32_32x32x16_bf16(v1, pfB[s - 2], oB, 0, 0, 0);
        }
    }

    // ---- epilogue: O^T[d][q=q32]; reg 4j+i -> d = dsb*32 + 8j + 4hi + i ----
    const float invl = 1.f / l_;
    float* orow = out + ((size_t)(b * N_ + qa)) * F_;
    #pragma unroll
    for (int dsb = 0; dsb < 2; ++dsb) {
        #pragma unroll
        for (int j = 0; j < 4; ++j) {
            const int ch = h * D_ + dsb * 32 + 8 * j + 4 * hi;
            float4 wv = *(const float4*)(wo + ch);
            float4 bv = *(const float4*)(bo + ch);
            float4 o4;
            if (dsb == 0) {
                o4.x = oA[4*j+0] * invl * wv.x + bv.x;
                o4.y = oA[4*j+1] * invl * wv.y + bv.y;
                o4.z = oA[4*j+2] * invl * wv.z + bv.z;
                o4.w = oA[4*j+3] * invl * wv.w + bv.w;
            } else {
                o4.x = oB[4*j+0] * invl * wv.x + bv.x;
                o4.y = oB[4*j+1] * invl * wv.y + bv.y;
                o4.z = oB[4*j+2] * invl * wv.z + bv.z;
                o4.w = oB[4*j+3] * invl * wv.w + bv.w;
            }
            *(float4*)(orow + ch) = o4;
        }
    }
}

// ---------------------------------------------------------------------------
// Fallback (round-1 kernel) if workspace is too small
// ---------------------------------------------------------------------------
__global__ void __launch_bounds__(256) attn_fused(
    const float* __restrict__ x,
    const float* __restrict__ wq, const float* __restrict__ bq,
    const float* __restrict__ wk, const float* __restrict__ bk,
    const float* __restrict__ wv, const float* __restrict__ bv,
    const float* __restrict__ wo, const float* __restrict__ bo,
    float* __restrict__ out)
{
    __shared__ short Klds[64][72];
    __shared__ short Vt[64][72];
    __shared__ short Plds[4][16][72];

    const int tid = threadIdx.x;
    const int wave = tid >> 6, lane = tid & 63;
    const int g = lane >> 4, cc = lane & 15;
    const int bid = blockIdx.x;
    const int qt = bid & 15, t1 = bid >> 4;
    const int h = t1 % H_, b = t1 / H_;

    const int qrow = qt * 64 + wave * 16 + cc;
    const float* xq = x + ((size_t)(b * N_ + qrow)) * F_ + h * D_;
    short8 qf[2];
    #pragma unroll
    for (int kc = 0; kc < 2; ++kc) {
        const int dd = kc * 32 + g * 8;
        float4 a0 = *(const float4*)(xq + dd);
        float4 a1 = *(const float4*)(xq + dd + 4);
        float qa[8] = {a0.x,a0.y,a0.z,a0.w,a1.x,a1.y,a1.z,a1.w};
        #pragma unroll
        for (int i = 0; i < 8; ++i) {
            const int ch = h * D_ + dd + i;
            qf[kc][i] = f2bf((qa[i] * wq[ch] + bq[ch]) * RSCALE);
        }
    }
    const int srow = tid >> 2, seg = tid & 3;
    const int cb = h * D_ + seg * 16;
    float m_[4], l_[4];
    f32x4 oacc[4];
    #pragma unroll
    for (int r = 0; r < 4; ++r) { m_[r] = -INFINITY; l_[r] = 0.f; oacc[r] = (f32x4){0,0,0,0}; }

    for (int nb = 0; nb < N_; nb += 64) {
        __syncthreads();
        {
            const float* xr = x + ((size_t)(b * N_ + nb + srow)) * F_ + cb;
            float4 x0 = *(const float4*)(xr + 0), x1 = *(const float4*)(xr + 4);
            float4 x2 = *(const float4*)(xr + 8), x3 = *(const float4*)(xr + 12);
            float xf[16] = {x0.x,x0.y,x0.z,x0.w,x1.x,x1.y,x1.z,x1.w,
                            x2.x,x2.y,x2.z,x2.w,x3.x,x3.y,x3.z,x3.w};
            short8 k0, k1;
            #pragma unroll
            for (int i = 0; i < 8; ++i) {
                k0[i] = f2bf(xf[i] * wk[cb+i] + bk[cb+i]);
                k1[i] = f2bf(xf[i+8] * wk[cb+i+8] + bk[cb+i+8]);
            }
            *(short8*)&Klds[srow][seg*16] = k0;
            *(short8*)&Klds[srow][seg*16+8] = k1;
            #pragma unroll
            for (int i = 0; i < 16; ++i)
                Vt[seg*16+i][srow] = f2bf(xf[i] * wv[cb+i] + bv[cb+i]);
        }
        __syncthreads();
        f32x4 s[4];
        #pragma unroll
        for (int sub = 0; sub < 4; ++sub) {
            f32x4 acc = (f32x4){0,0,0,0};
            #pragma unroll
            for (int kc = 0; kc < 2; ++kc) {
                short8 kf = *(short8*)&Klds[sub*16+cc][kc*32+g*8];
                acc = __builtin_amdgcn_mfma_f32_16x16x32_bf16(qf[kc], kf, acc, 0,0,0);
            }
            s[sub] = acc;
        }
        float tm[4];
        #pragma unroll
        for (int r = 0; r < 4; ++r)
            tm[r] = fmaxf(fmaxf(s[0][r], s[1][r]), fmaxf(s[2][r], s[3][r]));
        #pragma unroll
        for (int r = 0; r < 4; ++r)
            #pragma unroll
            for (int off = 1; off < 16; off <<= 1)
                tm[r] = fmaxf(tm[r], __shfl_xor(tm[r], off, 64));
        float corr[4], ps[4];
        #pragma unroll
        for (int r = 0; r < 4; ++r) {
            float mn = fmaxf(m_[r], tm[r]);
            corr[r] = __expf(m_[r] - mn);
            m_[r] = mn; ps[r] = 0.f;
        }
        #pragma unroll
        for (int sub = 0; sub < 4; ++sub)
            #pragma unroll
            for (int r = 0; r < 4; ++r) {
                float p = __expf(s[sub][r] - m_[r]);
                s[sub][r] = p; ps[r] += p;
            }
        #pragma unroll
        for (int r = 0; r < 4; ++r) {
            #pragma unroll
            for (int off = 1; off < 16; off <<= 1)
                ps[r] += __shfl_xor(ps[r], off, 64);
            l_[r] = l_[r] * corr[r] + ps[r];
        }
        #pragma unroll
        for (int d = 0; d < 4; ++d)
            #pragma unroll
            for (int r = 0; r < 4; ++r) oacc[d][r] *= corr[r];
        #pragma unroll
        for (int sub = 0; sub < 4; ++sub)
            #pragma unroll
            for (int r = 0; r < 4; ++r)
                Plds[wave][g*4+r][sub*16+cc] = f2bf(s[sub][r]);
        short8 pf[2];
        #pragma unroll
        for (int nc = 0; nc < 2; ++nc)
            pf[nc] = *(short8*)&Plds[wave][cc][nc*32+g*8];
        #pragma unroll
        for (int d = 0; d < 4; ++d)
            #pragma unroll
            for (int nc = 0; nc < 2; ++nc) {
                short8 vf = *(short8*)&Vt[d*16+cc][nc*32+g*8];
                oacc[d] = __builtin_amdgcn_mfma_f32_16x16x32_bf16(pf[nc], vf, oacc[d], 0,0,0);
            }
    }
    #pragma unroll
    for (int r = 0; r < 4; ++r) l_[r] = 1.f / l_[r];
    const int orow0 = qt * 64 + wave * 16 + g * 4;
    #pragma unroll
    for (int d = 0; d < 4; ++d) {
        const int ch = h * D_ + d * 16 + cc;
        const float wov = wo[ch], bov = bo[ch];
        #pragma unroll
        for (int r = 0; r < 4; ++r)
            out[((size_t)(b * N_ + orow0 + r)) * F_ + ch] = oacc[d][r] * l_[r] * wov + bov;
    }
}

extern "C" void kernel_launch(void* const* d_in, const int* in_sizes, int n_in,
                              void* d_out, int out_size, void* d_ws, size_t ws_size,
                              hipStream_t stream) {
    const float* x  = (const float*)d_in[0];
    const float* wq = (const float*)d_in[1];
    const float* bq = (const float*)d_in[2];
    const float* wk = (const float*)d_in[3];
    const float* bk = (const float*)d_in[4];
    const float* wv = (const float*)d_in[5];
    const float* bv = (const float*)d_in[6];
    const float* wo = (const float*)d_in[7];
    const float* bo = (const float*)d_in[8];
    float* out = (float*)d_out;

    const size_t elems = (size_t)B_ * H_ * N_ * D_;      // 12,582,912
    const size_t need  = elems * 2 * 2;                  // K + V, bf16
    if (ws_size >= need) {
        short* Ktw = (short*)d_ws;
        short* Vtw = Ktw + elems;
        prep_kv<<<dim3(B_ * H_ * NT), dim3(256), 0, stream>>>(x, wk, bk, wv, bv, Ktw, Vtw);
        attn_main<<<dim3(B_ * H_ * (N_ / QB)), dim3(256), 0, stream>>>(
            x, wq, bq, Ktw, Vtw, wo, bo, out);
    } else {
        attn_fused<<<dim3(B_ * H_ * (N_ / 64)), dim3(256), 0, stream>>>(
            x, wq, bq, wk, bk, wv, bv, wo, bo, out);
    }
}